// Round 3
// baseline (1438.698 us; speedup 1.0000x reference)
//
#include <hip/hip_runtime.h>
#include <hip/hip_cooperative_groups.h>
#include <math.h>

namespace cg = cooperative_groups;

// Fully-fused GCN(1->16)->lrelu->GCN(16->1)->lrelu->FC(100000->1024)->lrelu
// ->FC(1024->256)->log_softmax as ONE cooperative kernel (8 grid syncs).
// Scalar-factored convs (in_ch=1 / out_ch=1): each conv is a scalar scatter
// S[j] = sum_{e:dst=j} val[src], binned into per-partition LDS histograms.
// Grid = 96 chunks x 8 partitions = 768 blocks = 3 blocks/CU (50KB LDS each),
// which is exactly the cooperative co-residency capacity.

constexpr int NN    = 100000;
constexpr int NE    = 3200000;
constexpr int CONVC = 16;
constexpr int HID   = 1024;
constexpr int NOUT  = 256;
constexpr int P     = 8;       // node partitions
constexpr int PART  = 12800;   // nodes/partition -> 50 KB LDS
constexpr int C     = 96;      // edge chunks
constexpr int CHUNK = 33344;   // 96*33344 >= NE; every chunk length % 4 == 0
constexpr int GRID  = C * P;   // 768
constexpr int TPB   = 256;
constexpr int THIRD = 33336;   // mv1 column third (div by 4)
#define NEG 0.01f

__device__ __forceinline__ float lrelu(float x) { return x >= 0.0f ? x : NEG * x; }

__device__ __forceinline__ float wave_reduce_sum(float v) {
#pragma unroll
  for (int off = 32; off > 0; off >>= 1) v += __shfl_down(v, off, 64);
  return v;
}

// One binned pass: acc over LDS for partition p of chunk c, then plain-store
// the partial slice. val==nullptr => degree count.
__device__ void bin_pass(const int* __restrict__ src, const int* __restrict__ dst,
                         const float* __restrict__ val, float* __restrict__ partial,
                         float* acc, int bid, int tid) {
  int c = bid >> 3, p = bid & 7;
  for (int i = tid; i < PART; i += TPB) acc[i] = 0.0f;
  __syncthreads();
  int base = c * CHUNK;
  int lim = NE - base; if (lim > CHUNK) lim = CHUNK;
  int lo = p * PART;
  int lim4 = lim >> 2;
  const int4* d4p = reinterpret_cast<const int4*>(dst + base);
  if (val) {
    const int4* s4p = reinterpret_cast<const int4*>(src + base);
    for (int e = tid; e < lim4; e += TPB) {
      int4 d = d4p[e];
      int4 s = s4p[e];
      unsigned l;
      l = (unsigned)(d.x - lo); if (l < (unsigned)PART) atomicAdd(acc + l, val[s.x]);
      l = (unsigned)(d.y - lo); if (l < (unsigned)PART) atomicAdd(acc + l, val[s.y]);
      l = (unsigned)(d.z - lo); if (l < (unsigned)PART) atomicAdd(acc + l, val[s.z]);
      l = (unsigned)(d.w - lo); if (l < (unsigned)PART) atomicAdd(acc + l, val[s.w]);
    }
  } else {
    for (int e = tid; e < lim4; e += TPB) {
      int4 d = d4p[e];
      unsigned l;
      l = (unsigned)(d.x - lo); if (l < (unsigned)PART) atomicAdd(acc + l, 1.0f);
      l = (unsigned)(d.y - lo); if (l < (unsigned)PART) atomicAdd(acc + l, 1.0f);
      l = (unsigned)(d.z - lo); if (l < (unsigned)PART) atomicAdd(acc + l, 1.0f);
      l = (unsigned)(d.w - lo); if (l < (unsigned)PART) atomicAdd(acc + l, 1.0f);
    }
  }
  __syncthreads();
  float* outp = partial + (size_t)c * NN;
  int hi = NN - lo; if (hi > PART) hi = PART;
  for (int i = tid; i < hi; i += TPB) outp[lo + i] = acc[i];
}

__device__ __forceinline__ float col_sum(const float* __restrict__ partial, int i) {
  float s = 0.0f;
#pragma unroll 8
  for (int c = 0; c < C; c++) s += partial[(size_t)c * NN + i];
  return s;
}

__global__ __launch_bounds__(TPB, 3) void k_mega(
    const float* __restrict__ x, const int* __restrict__ src,
    const int* __restrict__ dst, const float* __restrict__ W1,
    const float* __restrict__ b1, const float* __restrict__ W2,
    const float* __restrict__ b2, const float* __restrict__ Wf1,
    const float* __restrict__ bf1, const float* __restrict__ Wf2,
    const float* __restrict__ bf2, float* __restrict__ out,
    float* __restrict__ ws) {
  cg::grid_group grid = cg::this_grid();
  __shared__ float acc[PART];
  int bid = blockIdx.x, tid = threadIdx.x;
  int gtid = bid * TPB + tid;

  float* partial = ws;                          // C*NN
  float* dinv    = partial + (size_t)C * NN;    // NN
  float* xs      = dinv + NN;                   // NN
  float* qv      = xs + NN;                     // NN
  float* xs2     = qv + NN;                     // NN
  float* v       = xs2 + NN;                    // NN
  float* zpart   = v + NN;                      // HID*3
  float* tmp     = zpart + (size_t)HID * 3;     // NOUT

  // P1: degree histogram
  bin_pass(nullptr, dst, nullptr, partial, acc, bid, tid);
  grid.sync();

  // P2: dinv = rsqrt(deg+1), xs = x*dinv
  if (gtid < NN) {
    float s = 1.0f + col_sum(partial, gtid);
    float di = rsqrtf(s);
    dinv[gtid] = di;
    xs[gtid] = x[gtid] * di;
  }
  grid.sync();

  // P3: scatter1 S1[j] = sum xs[src]
  bin_pass(src, dst, xs, partial, acc, bid, tid);
  grid.sync();

  // P4: conv1 epilogue + channel collapse -> qv, xs2 = qv*dinv
  if (gtid < NN) {
    float s = col_sum(partial, gtid);
    float di = dinv[gtid];
    float pv = di * (s + x[gtid] * di);
    float q = 0.0f;
#pragma unroll
    for (int ch = 0; ch < CONVC; ch++) q += lrelu(pv * W1[ch] + b1[ch]) * W2[ch];
    qv[gtid] = q;
    xs2[gtid] = q * di;
  }
  grid.sync();

  // P5: scatter2
  bin_pass(src, dst, xs2, partial, acc, bid, tid);
  grid.sync();

  // P6: conv2 epilogue -> v
  if (gtid < NN) {
    float s = col_sum(partial, gtid);
    float di = dinv[gtid];
    v[gtid] = lrelu(di * (s + qv[gtid] * di) + b2[0]);
  }
  grid.sync();

  // P7: mv1 partials. block = (g, t): rows {g, g+256, g+512, g+768}, col third t
  {
    int g = bid / 3, t = bid - 3 * g;
    int cb = t * THIRD, ce = cb + THIRD;
    if (ce > NN) ce = NN;
    const float4* v4 = reinterpret_cast<const float4*>(v);
    const float4* w0 = reinterpret_cast<const float4*>(Wf1 + (size_t)(g      ) * NN);
    const float4* w1 = reinterpret_cast<const float4*>(Wf1 + (size_t)(g + 256) * NN);
    const float4* w2 = reinterpret_cast<const float4*>(Wf1 + (size_t)(g + 512) * NN);
    const float4* w3 = reinterpret_cast<const float4*>(Wf1 + (size_t)(g + 768) * NN);
    float s0 = 0, s1 = 0, s2 = 0, s3 = 0;
    for (int j = cb / 4 + tid; j < ce / 4; j += TPB) {
      float4 vv = v4[j];
      float4 a = w0[j]; s0 += a.x * vv.x + a.y * vv.y + a.z * vv.z + a.w * vv.w;
      float4 b = w1[j]; s1 += b.x * vv.x + b.y * vv.y + b.z * vv.z + b.w * vv.w;
      float4 c = w2[j]; s2 += c.x * vv.x + c.y * vv.y + c.z * vv.z + c.w * vv.w;
      float4 d = w3[j]; s3 += d.x * vv.x + d.y * vv.y + d.z * vv.z + d.w * vv.w;
    }
    s0 = wave_reduce_sum(s0);
    s1 = wave_reduce_sum(s1);
    s2 = wave_reduce_sum(s2);
    s3 = wave_reduce_sum(s3);
    __syncthreads();  // acc reuse safety
    int w = tid >> 6;
    if ((tid & 63) == 0) {
      acc[w * 4 + 0] = s0; acc[w * 4 + 1] = s1;
      acc[w * 4 + 2] = s2; acc[w * 4 + 3] = s3;
    }
    __syncthreads();
    if (tid < 4) {
      float z = acc[tid] + acc[4 + tid] + acc[8 + tid] + acc[12 + tid];
      zpart[(g + 256 * tid) * 3 + t] = z;
    }
  }
  grid.sync();

  // P8: z finalize (inline) + mv2 -> tmp
  if (bid < NOUT) {
    float4 wv = reinterpret_cast<const float4*>(Wf2 + (size_t)bid * HID)[tid];
    float zz[4];
#pragma unroll
    for (int k = 0; k < 4; k++) {
      int h = tid * 4 + k;
      zz[k] = lrelu(zpart[h * 3] + zpart[h * 3 + 1] + zpart[h * 3 + 2] + bf1[h]);
    }
    float s = wv.x * zz[0] + wv.y * zz[1] + wv.z * zz[2] + wv.w * zz[3];
    s = wave_reduce_sum(s);
    __syncthreads();
    if ((tid & 63) == 0) acc[tid >> 6] = s;
    __syncthreads();
    if (tid == 0) tmp[bid] = acc[0] + acc[1] + acc[2] + acc[3] + bf2[bid];
  }
  grid.sync();

  // P9: log_softmax (block 0)
  if (bid == 0) {
    float vv = tmp[tid];
    float* buf = acc;
    buf[tid] = vv;
    __syncthreads();
    for (int s = 128; s > 0; s >>= 1) {
      if (tid < s) buf[tid] = fmaxf(buf[tid], buf[tid + s]);
      __syncthreads();
    }
    float m = buf[0];
    __syncthreads();
    buf[tid] = expf(vv - m);
    __syncthreads();
    for (int s = 128; s > 0; s >>= 1) {
      if (tid < s) buf[tid] += buf[tid + s];
      __syncthreads();
    }
    float lse = logf(buf[0]);
    out[tid] = vv - m - lse;
  }
}

extern "C" void kernel_launch(void* const* d_in, const int* in_sizes, int n_in,
                              void* d_out, int out_size, void* d_ws, size_t ws_size,
                              hipStream_t stream) {
  const float* x   = (const float*)d_in[0];
  const int*   ei  = (const int*)d_in[1];  // [2, E]: src row then dst row
  const float* W1c = (const float*)d_in[2];
  const float* b1c = (const float*)d_in[3];
  const float* W2c = (const float*)d_in[4];
  const float* b2c = (const float*)d_in[5];
  const float* Wf1 = (const float*)d_in[6];
  const float* bf1 = (const float*)d_in[7];
  const float* Wf2 = (const float*)d_in[8];
  const float* bf2 = (const float*)d_in[9];
  float* out = (float*)d_out;
  const int* src = ei;
  const int* dst = ei + NE;
  float* ws = (float*)d_ws;

  void* args[] = {(void*)&x,   (void*)&src, (void*)&dst, (void*)&W1c,
                  (void*)&b1c, (void*)&W2c, (void*)&b2c, (void*)&Wf1,
                  (void*)&bf1, (void*)&Wf2, (void*)&bf2, (void*)&out,
                  (void*)&ws};
  hipLaunchCooperativeKernel((const void*)k_mega, dim3(GRID), dim3(TPB), args,
                             0, stream);
}